// Round 16
// baseline (539.768 us; speedup 1.0000x reference)
//
#include <hip/hip_runtime.h>
#include <hip/hip_bf16.h>

#define B_ 64
#define T_ 512
#define D_ 1024
#define NCH 8   // t-chunks for c-reduction
#define TCH 64  // T_/NCH
#define MVKC 128  // K-chunk for batched matvec GEMM

// d_out element offsets (FLOAT32 elements)
#define OUT0_OFF 0u         // output [B,T,D]
#define OUT1_OFF 33554432u  // masks  [B,T,1]
#define OUT2_OFF 33587200u  // gcn    [B,T,D]
#define OUT3_OFF 67141632u  // att    [B,T]

typedef __attribute__((ext_vector_type(8))) short short8;
typedef __attribute__((ext_vector_type(4))) short short4v;
typedef __attribute__((ext_vector_type(4))) float f32x4;
typedef __attribute__((ext_vector_type(16))) float f32x16;

__device__ __forceinline__ short bf16_of(float x) {
    __hip_bfloat16 h = __float2bfloat16(x);
    return *reinterpret_cast<short*>(&h);
}
__device__ __forceinline__ float f32_of(short s) {
    unsigned u = (unsigned)(unsigned short)s << 16;
    float f;
    __builtin_memcpy(&f, &u, 4);
    return f;
}

// async global->LDS, 16B per lane; LDS dest is wave-uniform base + lane*16 (HW)
__device__ __forceinline__ void gload16(const void* g, void* l) {
    __builtin_amdgcn_global_load_lds(
        (__attribute__((address_space(1))) void*)(g),
        (__attribute__((address_space(3))) void*)(l), 16, 0, 0);
}

// ---- fused G-prep (ALL batches): Gs=bf16(G), Gt=bf16(G^T), o2=G passthrough,
// ---- pmax = per-128-row-chunk masked column max.  Tile: 128 rows x 32 cols.
__global__ __launch_bounds__(256) void prep_kernel(const float* __restrict__ in,
                                                   const int* __restrict__ subj_pos,
                                                   short* __restrict__ gs,
                                                   short* __restrict__ gt,
                                                   float* __restrict__ o2,
                                                   float* __restrict__ pmax) {
    __shared__ float tile[128][33];
    __shared__ int keep[128];
    __shared__ float pred[32][8];
    int z = blockIdx.z;
    int c0 = blockIdx.x * 32, r0 = blockIdx.y * 128;
    const float* inz = in + (size_t)z * T_ * D_;
    short* gsz = gs + (size_t)z * T_ * D_;
    short* gtz = gt + (size_t)z * D_ * T_;
    float* o2z = o2 + (size_t)z * T_ * D_;
    if (threadIdx.x < 128) keep[threadIdx.x] = (subj_pos[z * T_ + r0 + threadIdx.x] == 0);
    int tx = threadIdx.x & 7, ty = threadIdx.x >> 3;  // 8 f32x4-cols x 32 rows
    #pragma unroll
    for (int it = 0; it < 4; it++) {
        int r = ty + it * 32;
        size_t idx = (size_t)(r0 + r) * D_ + c0 + tx * 4;
        f32x4 v = *(const f32x4*)(inz + idx);
        *(f32x4*)(o2z + idx) = v;
        short4v s;
        #pragma unroll
        for (int q = 0; q < 4; q++) {
            s[q] = bf16_of(v[q]);
            tile[r][tx * 4 + q] = v[q];
        }
        *(short4v*)(gsz + idx) = s;
    }
    __syncthreads();
    // transposed write: 32 cols x 8 row-groups of 16 -> two short8 (16B) per thread
    int c = threadIdx.x >> 3, rg = (threadIdx.x & 7) * 16;
    short8 a0, a1;
    float pm = -1e12f;
    #pragma unroll
    for (int q = 0; q < 8; q++) {
        float v0 = tile[rg + q][c];
        float v1 = tile[rg + 8 + q][c];
        a0[q] = bf16_of(v0);
        a1[q] = bf16_of(v1);
        if (keep[rg + q]) pm = fmaxf(pm, v0);
        if (keep[rg + 8 + q]) pm = fmaxf(pm, v1);
    }
    size_t gidx = (size_t)(c0 + c) * T_ + r0 + rg;
    *(short8*)(gtz + gidx) = a0;
    *(short8*)(gtz + gidx + 8) = a1;
    pred[c][threadIdx.x & 7] = pm;
    __syncthreads();
    if (threadIdx.x < 32) {
        float mx = -1e12f;
        #pragma unroll
        for (int g = 0; g < 8; g++) mx = fmaxf(mx, pred[threadIdx.x][g]);
        pmax[((size_t)z * 4 + (r0 >> 7)) * D_ + c0 + threadIdx.x] = mx;
    }
}

// ---- pool reduce over 4 row-chunks ----
__global__ __launch_bounds__(256) void pool_red(const float* __restrict__ pmax,
                                                float* __restrict__ subj) {
    int d = threadIdx.x * 4;
    int b = blockIdx.y;
    f32x4 mx = {-1e12f, -1e12f, -1e12f, -1e12f};
    #pragma unroll
    for (int ch = 0; ch < 4; ch++) {
        f32x4 v = *(const f32x4*)(pmax + ((size_t)b * 4 + ch) * D_ + d);
        mx[0] = fmaxf(mx[0], v[0]);
        mx[1] = fmaxf(mx[1], v[1]);
        mx[2] = fmaxf(mx[2], v[2]);
        mx[3] = fmaxf(mx[3], v[3]);
    }
    *(f32x4*)(subj + (size_t)b * D_ + d) = mx;
}

// ---- batched matvec as split-K GEMM: pmv[kch][b][n] = sum_{k in chunk} x[b][k]*W[k][n] ----
__global__ __launch_bounds__(256) void mvg_part(const float* __restrict__ x0,
                                                const float* __restrict__ x1,
                                                const float* __restrict__ W,
                                                float* __restrict__ pmv) {
    __shared__ float xs[MVKC][64];
    __shared__ float ws[MVKC][64];
    int n0 = blockIdx.x * 64;
    int k0 = blockIdx.y * MVKC;
    for (int i = threadIdx.x; i < MVKC * 64; i += 256) {
        int k = i >> 6, b = i & 63;
        int kg = k0 + k;
        xs[k][b] = (kg < D_) ? x0[(size_t)b * D_ + kg]
                             : x1[(size_t)b * D_ + ((kg - D_) & (D_ - 1))];
    }
    for (int i = threadIdx.x; i < MVKC * 16; i += 256) {
        int r = i >> 4, c4 = (i & 15) * 4;
        *(f32x4*)&ws[r][c4] = *(const f32x4*)(W + (size_t)(k0 + r) * D_ + n0 + c4);
    }
    __syncthreads();
    int n = threadIdx.x & 63;
    int bg = (threadIdx.x >> 6) * 16;
    f32x4 acc[4] = {};
    for (int k = 0; k < MVKC; k++) {
        float wv = ws[k][n];
        #pragma unroll
        for (int g = 0; g < 4; g++) {
            f32x4 xv = *(const f32x4*)&xs[k][bg + g * 4];
            acc[g] += xv * wv;
        }
    }
    #pragma unroll
    for (int g = 0; g < 4; g++)
        #pragma unroll
        for (int q = 0; q < 4; q++)
            pmv[((size_t)blockIdx.y * 64 + bg + g * 4 + q) * D_ + n0 + n] = acc[g][q];
}

// ---- reduce matvec partials: y[b] = relu(bias + sum_kch pmv[kch][b]) ----
__global__ __launch_bounds__(256) void mvg_red(const float* __restrict__ pmv,
                                               const float* __restrict__ bias,
                                               float* __restrict__ y, int nkch) {
    int j = threadIdx.x * 4;
    int b = blockIdx.y;
    f32x4 acc = *(const f32x4*)(bias + j);
    for (int kch = 0; kch < nkch; kch++)
        acc += *(const f32x4*)(pmv + ((size_t)kch * 64 + b) * D_ + j);
    #pragma unroll
    for (int q = 0; q < 4; q++) acc[q] = fmaxf(acc[q], 0.f);
    *(f32x4*)(y + (size_t)b * D_ + j) = acc;
}

// ---------------- u = WK@bQ, w = WQ@bK, alpha = bK.bQ ----------------
__global__ __launch_bounds__(256) void vecs_kernel(const float* __restrict__ WKm,
                                                   const float* __restrict__ WQm,
                                                   const float* __restrict__ bKv,
                                                   const float* __restrict__ bQv,
                                                   float* __restrict__ u,
                                                   float* __restrict__ w,
                                                   float* __restrict__ alpha) {
    int tid = threadIdx.x, wave = tid >> 6, lane = tid & 63;
    int row = blockIdx.x * 4 + wave;
    float s1 = 0.f, s2 = 0.f;
    for (int c = lane; c < D_; c += 64) {
        s1 += WKm[(size_t)row * D_ + c] * bQv[c];
        s2 += WQm[(size_t)row * D_ + c] * bKv[c];
    }
    #pragma unroll
    for (int off = 32; off; off >>= 1) {
        s1 += __shfl_xor(s1, off);
        s2 += __shfl_xor(s2, off);
    }
    if (lane == 0) { u[row] = s1; w[row] = s2; }
    if (blockIdx.x == 0 && wave == 0) {
        float a = 0.f;
        for (int c = lane; c < D_; c += 64) a += bKv[c] * bQv[c];
        #pragma unroll
        for (int off = 32; off; off >>= 1) a += __shfl_xor(a, off);
        if (lane == 0) alpha[0] = a;
    }
}

// ---- fused row dots on bf16 Gs: Gu=g.u+alpha, Gw=g.w, lg=g.(tv*Wk)+bk (1 wave/row) ----
__global__ __launch_bounds__(256) void att_dots(const short* __restrict__ gs,
                                                const float* __restrict__ u,
                                                const float* __restrict__ w,
                                                const float* __restrict__ tv,
                                                const float* __restrict__ Wk,
                                                const float* __restrict__ alpha,
                                                const float* __restrict__ bk,
                                                float* __restrict__ Gu,
                                                float* __restrict__ Gw,
                                                float* __restrict__ lg) {
    __shared__ float su[D_], sw[D_], s2[D_];
    int tid = threadIdx.x, wave = tid >> 6, lane = tid & 63;
    size_t row0 = (size_t)blockIdx.x * 4;
    int b = (int)(row0 >> 9);
    for (int c = tid; c < D_; c += 256) {
        su[c] = u[c];
        sw[c] = w[c];
        s2[c] = tv[(size_t)b * D_ + c] * Wk[c];
    }
    __syncthreads();
    size_t row = row0 + wave;
    const short* g = gs + row * D_;
    float d1 = 0.f, d2 = 0.f, d3 = 0.f;
    #pragma unroll
    for (int it = 0; it < 4; it++) {
        int c = lane * 4 + it * 256;
        short4v gv = *(const short4v*)(g + c);
        #pragma unroll
        for (int q = 0; q < 4; q++) {
            float gq = f32_of(gv[q]);
            d1 += gq * su[c + q];
            d2 += gq * sw[c + q];
            d3 += gq * s2[c + q];
        }
    }
    #pragma unroll
    for (int off = 32; off; off >>= 1) {
        d1 += __shfl_xor(d1, off);
        d2 += __shfl_xor(d2, off);
        d3 += __shfl_xor(d3, off);
    }
    if (lane == 0) {
        Gu[row] = d1 + alpha[0];
        Gw[row] = d2;
        lg[row] = d3 + bk[0];
    }
}

// ---- k-softmax over T per batch, in place ----
__global__ __launch_bounds__(256) void ksoftmax_kernel(float* __restrict__ lg) {
    __shared__ float red[4];
    int b = blockIdx.x, tid = threadIdx.x;
    int wave = tid >> 6, lane = tid & 63;
    float* L = lg + (size_t)b * T_;
    float v0 = L[tid], v1 = L[tid + 256];
    float mx = fmaxf(v0, v1);
    #pragma unroll
    for (int off = 32; off; off >>= 1) mx = fmaxf(mx, __shfl_xor(mx, off));
    if (lane == 0) red[wave] = mx;
    __syncthreads();
    mx = fmaxf(fmaxf(red[0], red[1]), fmaxf(red[2], red[3]));
    __syncthreads();
    float e0 = expf(v0 - mx), e1 = expf(v1 - mx);
    float zs = e0 + e1;
    #pragma unroll
    for (int off = 32; off; off >>= 1) zs += __shfl_xor(zs, off);
    if (lane == 0) red[wave] = zs;
    __syncthreads();
    float invZ = 1.f / (red[0] + red[1] + red[2] + red[3]);
    L[tid] = e0 * invZ;
    L[tid + 256] = e1 * invZ;
}

// ---- partial c from bf16 Gs ----
__global__ __launch_bounds__(256) void csum_part(const short* __restrict__ gs,
                                                 const float* __restrict__ k,
                                                 float* __restrict__ part) {
    __shared__ float kv[TCH];
    int d = threadIdx.x * 4;
    int ch = blockIdx.y, b = blockIdx.z;
    if (threadIdx.x < TCH) kv[threadIdx.x] = k[(size_t)b * T_ + ch * TCH + threadIdx.x];
    __syncthreads();
    const short* gb = gs + ((size_t)b * T_ + ch * TCH) * D_ + d;
    f32x4 acc = {};
    #pragma unroll 4
    for (int i = 0; i < TCH; i++) {
        short4v gv = *(const short4v*)(gb + (size_t)i * D_);
        #pragma unroll
        for (int q = 0; q < 4; q++) acc[q] += kv[i] * f32_of(gv[q]);
    }
    *(f32x4*)(part + ((size_t)b * NCH + ch) * D_ + d) = acc;
}

// ---- reduce partials: c[b,d] = sum_ch part ----
__global__ __launch_bounds__(256) void csum_reduce(const float* __restrict__ part,
                                                   float* __restrict__ cbuf) {
    int d = threadIdx.x * 4;
    int b = blockIdx.y;
    f32x4 acc = {};
    #pragma unroll
    for (int ch = 0; ch < NCH; ch++)
        acc += *(const f32x4*)(part + ((size_t)b * NCH + ch) * D_ + d);
    *(f32x4*)(cbuf + (size_t)b * D_ + d) = acc;
}

// ---------------- plain cast f32 -> bf16, vectorized ----------------
__global__ __launch_bounds__(256) void cast_kernel(const float* __restrict__ in,
                                                   short* __restrict__ out, size_t n8) {
    size_t i = (size_t)blockIdx.x * 256 + threadIdx.x;
    size_t stride = (size_t)gridDim.x * 256;
    for (; i < n8; i += stride) {
        f32x4 v0 = ((const f32x4*)in)[2 * i];
        f32x4 v1 = ((const f32x4*)in)[2 * i + 1];
        short8 o;
        #pragma unroll
        for (int j = 0; j < 4; j++) {
            o[j] = bf16_of(v0[j]);
            o[4 + j] = bf16_of(v1[j]);
        }
        ((short8*)out)[i] = o;
    }
}

// ---------------- out[z][c][r] = bf16(in[z][r][c]) ----------------
__global__ __launch_bounds__(256) void transpose_kernel(const float* __restrict__ in, size_t sIn,
                                                        short* __restrict__ out, size_t sOut,
                                                        int R, int C) {
    __shared__ float tile[32][33];
    int z = blockIdx.z;
    in += (size_t)z * sIn;
    out += (size_t)z * sOut;
    int c0 = blockIdx.x * 32, r0 = blockIdx.y * 32;
    int tx = threadIdx.x & 31, ty = threadIdx.x >> 5;
    #pragma unroll
    for (int i = 0; i < 4; i++) {
        int r = ty + i * 8;
        tile[r][tx] = in[(size_t)(r0 + r) * C + c0 + tx];
    }
    __syncthreads();
    #pragma unroll
    for (int i = 0; i < 4; i++) {
        int c = ty + i * 8;
        out[(size_t)(c0 + c) * R + r0 + tx] = bf16_of(tile[tx][c]);
    }
}

// ================= MFMA NT bf16 GEMM: 256x256 tile, deep-pipelined =================
// BK=64 split in 2 k-halves; 512 thr = 8 waves (2M x 4N); per-wave 128x64 via
// 4x2 32x32x16 frags (acc 128 VGPR). LDS 128KB: [buf][A|B][khalf][256 rows][32 k].
// Phases per tile: p0=(Mlo,k0) p1=(Mhi,k0) | barrier | p2=(Mlo,k1) p3=(Mhi,k1).
// Stage issue: p0->A-k1(t+1), p1->B-k1(t+1) (other buf; dead since last tile);
//              p2->A-k0(t+2), p3->B-k0(t+2) (current buf; k0 dead after mid barrier).
// Tile-start: counted s_waitcnt vmcnt(4) (k0(t+1) stays in flight) + s_barrier.
// Slot swizzle: LDS 16B slot s holds global slot s ^ ((row>>1)&3); linear dest,
// inverse-swizzled global source, swizzled ds_read (both-sides rule).
// MODE 0: f32 | 1: f32 + Gu[row]+Gw[col] | 2: bf16 | 3: f32 (acc+bV[col])*gate
template <int MODE>
__global__ __launch_bounds__(512) void gemm_nt(
        const short* __restrict__ A, size_t sAz,
        const short* __restrict__ Bt, size_t sBz,
        int K, int ldout,
        float* __restrict__ Cf, short* __restrict__ Cb, size_t sCz,
        const float* __restrict__ e1, const float* __restrict__ e2) {
    __shared__ __align__(16) short lds[65536];  // 128 KB
    unsigned gx = gridDim.x, gy = gridDim.y;
    unsigned lin = blockIdx.x + gx * (blockIdx.y + gy * blockIdx.z);
    unsigned tot = gx * gy * gridDim.z;
    unsigned swz = (lin & 7u) * (tot >> 3) + (lin >> 3);
    unsigned bx = swz % gx;
    unsigned tmp = swz / gx;
    unsigned by = tmp % gy;
    unsigned bz = tmp / gy;

    int z = bz;
    A += (size_t)z * sAz;
    Bt += (size_t)z * sBz;
    int tid = threadIdx.x;
    int lane = tid & 63, wave = tid >> 6;
    int wr = wave >> 2, wc = wave & 3;
    size_t rowBase = (size_t)bx * 256;
    size_t colBase = (size_t)by * 256;

    int srcslot = (lane & 3) ^ ((lane >> 3) & 3);  // inverse-swizzled global 16B slot
    int srow = lane >> 2;                          // row within 16-row chunk
    int rxor = (lane >> 1) & 3;                    // read-side swizzle
    int khi = lane >> 5;                           // k sub-slot (0/1)
    const int NT = K >> 6;

// stage one 16KB half-tile (256 rows x 32 k), 2 gload16/thread; ldsoff in shorts
#define STAGE(gptr, base, kb, h, ldsoff)                                           \
    {                                                                              \
        _Pragma("unroll")                                                          \
        for (int q = 0; q < 2; q++) {                                              \
            int ch = wave * 2 + q;                                                 \
            const short* _s = (gptr) + ((base) + ch * 16 + srow) * (size_t)K       \
                              + (kb) + (h) * 32 + srcslot * 8;                     \
            gload16(_s, lds + (ldsoff) + ch * 512);                                \
        }                                                                          \
    }

// compute one phase: M-half mh, k-half h, buffer offset boff; 8 ds_read + 8 MFMA
#define PHASE(mh, h, boff)                                                         \
    {                                                                              \
        const short* _as = lds + (boff) + (h) * 8192;                              \
        const short* _bs = lds + (boff) + 16384 + (h) * 8192;                      \
        short8 af[2][2], bq[2][2];                                                 \
        _Pragma("unroll")                                                          \
        for (int sl = 0; sl < 2; sl++) {                                           \
            int slot = ((sl * 2 + khi) ^ rxor) * 8;                                \
            _Pragma("unroll")                                                      \
            for (int i = 0; i < 2; i++) {                                          \
                int row = wr * 128 + ((mh) * 2 + i) * 32 + (lane & 31);            \
                af[i][sl] = *(const short8*)(_as + row * 32 + slot);               \
            }                                                                      \
            _Pragma("unroll")                                                      \
            for (int j = 0; j < 2; j++) {                                          \
                int row = wc * 64 + j * 32 + (lane & 31);                          \
                bq[j][sl] = *(const short8*)(_bs + row * 32 + slot);               \
            }                                                                      \
        }                                                                          \
        __builtin_amdgcn_s_setprio(1);                                             \
        _Pragma("unroll")                                                          \
        for (int sl = 0; sl < 2; sl++)                                             \
            _Pragma("unroll")                                                      \
            for (int i = 0; i < 2; i++)                                            \
                _Pragma("unroll")                                                  \
                for (int j = 0; j < 2; j++)                                        \
                    acc[(mh) * 2 + i][j] = __builtin_amdgcn_mfma_f32_32x32x16_bf16(\
                        af[i][sl], bq[j][sl], acc[(mh) * 2 + i][j], 0, 0, 0);      \
        __builtin_amdgcn_s_setprio(0);                                             \
    }

    f32x16 acc[4][2] = {};

    // prologue: tile0 full (Ak0,Bk0,Ak1,Bk1 -> buf0), tile1 k0 (A,B -> buf1)
    STAGE(A, rowBase, 0, 0, 0);
    STAGE(Bt, colBase, 0, 0, 16384);
    STAGE(A, rowBase, 0, 1, 8192);
    STAGE(Bt, colBase, 0, 1, 16384 + 8192);
    STAGE(A, rowBase, 64, 0, 32768);
    STAGE(Bt, colBase, 64, 0, 32768 + 16384);

    for (int t = 0; t < NT; t++) {
        int boff = (t & 1) * 32768;
        int ooff = boff ^ 32768;
        if (t == NT - 1) {
            asm volatile("s_waitcnt vmcnt(0)" ::: "memory");
        } else {
            asm volatile("s_waitcnt vmcnt(4)" ::: "memory");
        }
        __builtin_amdgcn_s_barrier();
        if (t + 1 < NT) STAGE(A, rowBase, (t + 1) * 64, 1, ooff + 8192);
        PHASE(0, 0, boff);
        if (t + 1 < NT) STAGE(Bt, colBase, (t + 1) * 64, 1, ooff + 16384 + 8192);
        PHASE(1, 0, boff);
        asm volatile("s_waitcnt lgkmcnt(0)" ::: "memory");
        __builtin_amdgcn_s_barrier();
        if (t + 2 < NT) STAGE(A, rowBase, (t + 2) * 64, 0, boff);
        PHASE(0, 1, boff);
        if (t + 2 < NT) STAGE(Bt, colBase, (t + 2) * 64, 0, boff + 16384);
        PHASE(1, 1, boff);
        asm volatile("s_waitcnt lgkmcnt(0)" ::: "memory");
    }

    #pragma unroll
    for (int i = 0; i < 4; i++) {
        #pragma unroll
        for (int j = 0; j < 2; j++) {
            #pragma unroll
            for (int r = 0; r < 16; r++) {
                size_t row = rowBase + wr * 128 + i * 32 + (r & 3) + 8 * (r >> 2) + 4 * khi;
                size_t col = colBase + wc * 64 + j * 32 + (lane & 31);
                float v = acc[i][j][r];
                if (MODE == 0) {
                    Cf[z * sCz + row * ldout + col] = v;
                } else if (MODE == 1) {
                    Cf[z * sCz + row * ldout + col] = v + e1[z * T_ + row] + e2[z * T_ + col];
                } else if (MODE == 2) {
                    Cb[z * sCz + row * ldout + col] = bf16_of(v);
                } else {
                    Cf[z * sCz + row * ldout + col] = (v + e1[col]) * e2[(size_t)z * D_ + col];
                }
            }
        }
    }
#undef STAGE
#undef PHASE
}

// ---------------- per-row: att out (f32) + probs out (bf16); 4 rows/block ----------------
__global__ __launch_bounds__(256) void softmax_att(const float* __restrict__ S,
                                                   short* __restrict__ probs,
                                                   float* __restrict__ att) {
    const float SCALE = 0.03125f;  // 1/32
    int wave = threadIdx.x >> 6, lane = threadIdx.x & 63;
    int t = blockIdx.x * 4 + wave, z = blockIdx.y;
    const float* row = S + ((size_t)z * T_ + t) * T_;
    short* prow = probs + ((size_t)z * T_ + t) * T_;
    float v[8];
    float mx = -1e30f;
    #pragma unroll
    for (int k = 0; k < 8; k++) {
        v[k] = row[lane + k * 64];
        mx = fmaxf(mx, v[k]);
    }
    #pragma unroll
    for (int off = 32; off; off >>= 1) mx = fmaxf(mx, __shfl_xor(mx, off));
    float z1 = 0.f, z2 = 0.f, dg = 0.f;
    #pragma unroll
    for (int k = 0; k < 8; k++) {
        float x = v[k] - mx;
        float e2 = expf(x * SCALE);
        float p = e2 * e2;
        p = p * p;
        p = p * p;
        p = p * p;
        p = p * p;  // e^x
        z1 += p;
        z2 += e2;
        if (lane + k * 64 == t) dg = p;
        v[k] = e2;
    }
    #pragma unroll
    for (int off = 32; off; off >>= 1) {
        z1 += __shfl_xor(z1, off);
        z2 += __shfl_xor(z2, off);
        dg += __shfl_xor(dg, off);
    }
    float inv2 = 1.f / z2;
    #pragma unroll
    for (int k = 0; k < 8; k++) prow[lane + k * 64] = bf16_of(v[k] * inv2);
    if (lane == 0) att[z * T_ + t] = SCALE * (1.f - dg / z1);
}

// ---------------- masks passthrough (f32) ----------------
__global__ __launch_bounds__(256) void masks_kernel(const int* __restrict__ masks,
                                                    float* __restrict__ out_masks) {
    int i = blockIdx.x * 256 + threadIdx.x;
    if (i < B_ * T_) out_masks[i] = (float)masks[i];
}

extern "C" void kernel_launch(void* const* d_in, const int* in_sizes, int n_in,
                              void* d_out, int out_size, void* d_ws, size_t ws_size,
                              hipStream_t stream) {
    const float* gcn = (const float*)d_in[0];
    const int* subj_pos = (const int*)d_in[1];
    const int* masks = (const int*)d_in[3];
    const float* Wq = (const float*)d_in[4];
    const float* bq = (const float*)d_in[5];
    const float* Wc = (const float*)d_in[6];
    const float* bc = (const float*)d_in[7];
    const float* Wk = (const float*)d_in[8];
    const float* bk = (const float*)d_in[9];
    const float* Wm = (const float*)d_in[10];
    const float* bm = (const float*)d_in[11];
    const float* WK = (const float*)d_in[12];
    const float* bK = (const float*)d_in[13];
    const float* WQ = (const float*)d_in[14];
    const float* bQ = (const float*)d_in[15];
    const float* WV = (const float*)d_in[16];
    const float* bV = (const float*)d_in[17];

    float* out = (float*)d_out;

    // ---- workspace layout ----
    char* p = (char*)d_ws;
    auto alloc = [&](size_t bytes) {
        char* r = p;
        p += (bytes + 255) & ~(size_t)255;
        return r;
    };
    float* subj = (float*)alloc(B_ * D_ * 4);
    float* qv   = (float*)alloc(B_ * D_ * 4);
    float* tv   = (float*)alloc(B_ * D_ * 4);
    float* cb   = (float*)alloc(B_ * D_ * 4);
    float* mb   = (float*)alloc(B_ * D_ * 4);
    float* u    = (float*)alloc(D_ * 4);
    float* w    = (float*)alloc(D_ * 4);
    float* alph = (float*)alloc(256);
    float* Gu   = (float*)alloc(B_ * T_ * 4);
    float* Gw   = (float*)alloc(B_ * T_ * 4);
    float* lg   = (float*)alloc(B_ * T_ * 4);
    float* part = (float*)alloc((size_t)B_ * NCH * D_ * 4);
    float* pmax = (float*)alloc((size_t)B_ * 4 * D_ * 4);
    float* pmv  = (float*)alloc((size_t)24 * 64 * D_ * 4);
    short* WKb  = (short*)alloc((size_t)D_ * D_ * 2);
    short* WQb  = (short*)alloc((size_t)D_ * D_ * 2);
    short* Ptb  = (short*)alloc((size_t)D_ * D_ * 2);
    short* WVt  = (short*)alloc((size_t)D_ * D_ * 2);
    short* Gs   = (short*)alloc((size_t)B_ * T_ * D_ * 2);  // full, all batches
    short* Gt   = (short*)alloc((size_t)B_ * D_ * T_ * 2);  // full, all batches

    size_t fixedBytes = (size_t)(p - (char*)d_ws);
    const size_t perBatch = (size_t)T_ * D_ * 2   // Ys
                          + (size_t)T_ * T_ * 4   // S
                          + (size_t)T_ * T_ * 2   // probs
                          + (size_t)T_ * D_ * 2;  // Zs
    int nc = 64;
    while (nc > 1 && fixedBytes + (size_t)nc * perBatch + 4096 > ws_size) nc >>= 1;

    short* Ys_c    = (short*)alloc((size_t)nc * T_ * D_ * 2);
    float* S_c     = (float*)alloc((size_t)nc * T_ * T_ * 4);
    short* probs_c = (short*)alloc((size_t)nc * T_ * T_ * 2);
    short* Zs_c    = (short*)alloc((size_t)nc * T_ * D_ * 2);

    // ---- weight precompute ----
    cast_kernel<<<512, 256, 0, stream>>>(WK, WKb, (size_t)D_ * D_ / 8);
    cast_kernel<<<512, 256, 0, stream>>>(WQ, WQb, (size_t)D_ * D_ / 8);
    gemm_nt<2><<<dim3(4, 4, 1), 512, 0, stream>>>(WQb, 0, WKb, 0, D_, D_,
                                                  nullptr, Ptb, 0, nullptr, nullptr);
    transpose_kernel<<<dim3(32, 32, 1), 256, 0, stream>>>(WV, 0, WVt, 0, D_, D_);

    // ---- prep ALL batches: Gs/Gt/out2/pool-partials in one gcn pass ----
    prep_kernel<<<dim3(D_ / 32, T_ / 128, B_), 256, 0, stream>>>(
        gcn, subj_pos, Gs, Gt, out + OUT2_OFF, pmax);

    // ---- small path ----
    pool_red<<<dim3(1, B_), 256, 0, stream>>>(pmax, subj);
    mvg_part<<<dim3(D_ / 64, 16), 256, 0, stream>>>(subj, subj, Wq, pmv);
    mvg_red<<<dim3(1, B_), 256, 0, stream>>>(pmv, bq, qv, 16);
    mvg_part<<<dim3(D_ / 64, 8), 256, 0, stream>>>(qv, qv, Wc, pmv);
    mvg_red<<<dim3(1, B_), 256, 0, stream>>>(pmv, bc, tv, 8);
    vecs_kernel<<<D_ / 4, 256, 0, stream>>>(WK, WQ, bK, bQ, u, w, alph);
    att_dots<<<B_ * T_ / 4, 256, 0, stream>>>(Gs, u, w, tv, Wk, alph, bk, Gu, Gw, lg);
    ksoftmax_kernel<<<B_, 256, 0, stream>>>(lg);
    csum_part<<<dim3(1, NCH, B_), 256, 0, stream>>>(Gs, lg, part);
    csum_reduce<<<dim3(1, B_), 256, 0, stream>>>(part, cb);
    mvg_part<<<dim3(D_ / 64, 24), 256, 0, stream>>>(cb, subj, Wm, pmv);
    mvg_red<<<dim3(1, B_), 256, 0, stream>>>(pmv, bm, mb, 24);

    // ---- chunked attention ----
    for (int b0 = 0; b0 < B_; b0 += nc) {
        const short* Gsc = Gs + (size_t)b0 * T_ * D_;
        const short* Gtc = Gt + (size_t)b0 * D_ * T_;
        // Y = G@M
        gemm_nt<2><<<dim3(nc * T_ / 256, D_ / 256, 1), 512, 0, stream>>>(
            Gsc, 0, Ptb, 0, D_, D_, nullptr, Ys_c, 0, nullptr, nullptr);
        // S = Y@G^T + Gu + Gw
        gemm_nt<1><<<dim3(T_ / 256, T_ / 256, nc), 512, 0, stream>>>(
            Ys_c, (size_t)T_ * D_, Gsc, (size_t)T_ * D_, D_, T_,
            S_c, nullptr, (size_t)T_ * T_, Gu + (size_t)b0 * T_, Gw + (size_t)b0 * T_);
        // softmax: att (f32) + probs (bf16)
        softmax_att<<<dim3(T_ / 4, nc), 256, 0, stream>>>(S_c, probs_c, out + OUT3_OFF + (size_t)b0 * T_);
        // Z = probs@G
        gemm_nt<2><<<dim3(T_ / 256, D_ / 256, nc), 512, 0, stream>>>(
            probs_c, (size_t)T_ * T_, Gtc, (size_t)D_ * T_, T_, D_,
            nullptr, Zs_c, (size_t)T_ * D_, nullptr, nullptr);
        // out0 = (Z@WV + bV) * m
        gemm_nt<3><<<dim3(T_ / 256, D_ / 256, nc), 512, 0, stream>>>(
            Zs_c, (size_t)T_ * D_, WVt, 0, D_, D_,
            out + OUT0_OFF + (size_t)b0 * T_ * D_, nullptr, (size_t)T_ * D_,
            bV, mb + (size_t)b0 * D_);
    }

    // ---- masks passthrough ----
    masks_kernel<<<(B_ * T_ + 255) / 256, 256, 0, stream>>>(masks, out + OUT1_OFF);
}

// Round 17
// 538.042 us; speedup vs baseline: 1.0032x; 1.0032x over previous
//
#include <hip/hip_runtime.h>
#include <hip/hip_bf16.h>

#define B_ 64
#define T_ 512
#define D_ 1024
#define NCH 8   // t-chunks for c-reduction
#define TCH 64  // T_/NCH
#define MVKC 128  // K-chunk for batched matvec GEMM

// d_out element offsets (FLOAT32 elements)
#define OUT0_OFF 0u         // output [B,T,D]
#define OUT1_OFF 33554432u  // masks  [B,T,1]
#define OUT2_OFF 33587200u  // gcn    [B,T,D]
#define OUT3_OFF 67141632u  // att    [B,T]

typedef __attribute__((ext_vector_type(8))) short short8;
typedef __attribute__((ext_vector_type(4))) short short4v;
typedef __attribute__((ext_vector_type(4))) float f32x4;
typedef __attribute__((ext_vector_type(16))) float f32x16;

__device__ __forceinline__ short bf16_of(float x) {
    __hip_bfloat16 h = __float2bfloat16(x);
    return *reinterpret_cast<short*>(&h);
}
__device__ __forceinline__ float f32_of(short s) {
    unsigned u = (unsigned)(unsigned short)s << 16;
    float f;
    __builtin_memcpy(&f, &u, 4);
    return f;
}

// async global->LDS, 16B per lane; LDS dest is wave-uniform base + lane*16 (HW)
__device__ __forceinline__ void gload16(const void* g, void* l) {
    __builtin_amdgcn_global_load_lds(
        (__attribute__((address_space(1))) void*)(g),
        (__attribute__((address_space(3))) void*)(l), 16, 0, 0);
}

// ---- fused G-prep (ALL batches): Gs=bf16(G), Gt=bf16(G^T), o2=G passthrough,
// ---- pmax = per-128-row-chunk masked column max.  Tile: 128 rows x 32 cols.
__global__ __launch_bounds__(256) void prep_kernel(const float* __restrict__ in,
                                                   const int* __restrict__ subj_pos,
                                                   short* __restrict__ gs,
                                                   short* __restrict__ gt,
                                                   float* __restrict__ o2,
                                                   float* __restrict__ pmax) {
    __shared__ float tile[128][33];
    __shared__ int keep[128];
    __shared__ float pred[32][8];
    int z = blockIdx.z;
    int c0 = blockIdx.x * 32, r0 = blockIdx.y * 128;
    const float* inz = in + (size_t)z * T_ * D_;
    short* gsz = gs + (size_t)z * T_ * D_;
    short* gtz = gt + (size_t)z * D_ * T_;
    float* o2z = o2 + (size_t)z * T_ * D_;
    if (threadIdx.x < 128) keep[threadIdx.x] = (subj_pos[z * T_ + r0 + threadIdx.x] == 0);
    int tx = threadIdx.x & 7, ty = threadIdx.x >> 3;  // 8 f32x4-cols x 32 rows
    #pragma unroll
    for (int it = 0; it < 4; it++) {
        int r = ty + it * 32;
        size_t idx = (size_t)(r0 + r) * D_ + c0 + tx * 4;
        f32x4 v = *(const f32x4*)(inz + idx);
        *(f32x4*)(o2z + idx) = v;
        short4v s;
        #pragma unroll
        for (int q = 0; q < 4; q++) {
            s[q] = bf16_of(v[q]);
            tile[r][tx * 4 + q] = v[q];
        }
        *(short4v*)(gsz + idx) = s;
    }
    __syncthreads();
    // transposed write: 32 cols x 8 row-groups of 16 -> two short8 (16B) per thread
    int c = threadIdx.x >> 3, rg = (threadIdx.x & 7) * 16;
    short8 a0, a1;
    float pm = -1e12f;
    #pragma unroll
    for (int q = 0; q < 8; q++) {
        float v0 = tile[rg + q][c];
        float v1 = tile[rg + 8 + q][c];
        a0[q] = bf16_of(v0);
        a1[q] = bf16_of(v1);
        if (keep[rg + q]) pm = fmaxf(pm, v0);
        if (keep[rg + 8 + q]) pm = fmaxf(pm, v1);
    }
    size_t gidx = (size_t)(c0 + c) * T_ + r0 + rg;
    *(short8*)(gtz + gidx) = a0;
    *(short8*)(gtz + gidx + 8) = a1;
    pred[c][threadIdx.x & 7] = pm;
    __syncthreads();
    if (threadIdx.x < 32) {
        float mx = -1e12f;
        #pragma unroll
        for (int g = 0; g < 8; g++) mx = fmaxf(mx, pred[threadIdx.x][g]);
        pmax[((size_t)z * 4 + (r0 >> 7)) * D_ + c0 + threadIdx.x] = mx;
    }
}

// ---- pool reduce over 4 row-chunks ----
__global__ __launch_bounds__(256) void pool_red(const float* __restrict__ pmax,
                                                float* __restrict__ subj) {
    int d = threadIdx.x * 4;
    int b = blockIdx.y;
    f32x4 mx = {-1e12f, -1e12f, -1e12f, -1e12f};
    #pragma unroll
    for (int ch = 0; ch < 4; ch++) {
        f32x4 v = *(const f32x4*)(pmax + ((size_t)b * 4 + ch) * D_ + d);
        mx[0] = fmaxf(mx[0], v[0]);
        mx[1] = fmaxf(mx[1], v[1]);
        mx[2] = fmaxf(mx[2], v[2]);
        mx[3] = fmaxf(mx[3], v[3]);
    }
    *(f32x4*)(subj + (size_t)b * D_ + d) = mx;
}

// ---- batched matvec as split-K GEMM: pmv[kch][b][n] = sum_{k in chunk} x[b][k]*W[k][n] ----
__global__ __launch_bounds__(256) void mvg_part(const float* __restrict__ x0,
                                                const float* __restrict__ x1,
                                                const float* __restrict__ W,
                                                float* __restrict__ pmv) {
    __shared__ float xs[MVKC][64];
    __shared__ float ws[MVKC][64];
    int n0 = blockIdx.x * 64;
    int k0 = blockIdx.y * MVKC;
    for (int i = threadIdx.x; i < MVKC * 64; i += 256) {
        int k = i >> 6, b = i & 63;
        int kg = k0 + k;
        xs[k][b] = (kg < D_) ? x0[(size_t)b * D_ + kg]
                             : x1[(size_t)b * D_ + ((kg - D_) & (D_ - 1))];
    }
    for (int i = threadIdx.x; i < MVKC * 16; i += 256) {
        int r = i >> 4, c4 = (i & 15) * 4;
        *(f32x4*)&ws[r][c4] = *(const f32x4*)(W + (size_t)(k0 + r) * D_ + n0 + c4);
    }
    __syncthreads();
    int n = threadIdx.x & 63;
    int bg = (threadIdx.x >> 6) * 16;
    f32x4 acc[4] = {};
    for (int k = 0; k < MVKC; k++) {
        float wv = ws[k][n];
        #pragma unroll
        for (int g = 0; g < 4; g++) {
            f32x4 xv = *(const f32x4*)&xs[k][bg + g * 4];
            acc[g] += xv * wv;
        }
    }
    #pragma unroll
    for (int g = 0; g < 4; g++)
        #pragma unroll
        for (int q = 0; q < 4; q++)
            pmv[((size_t)blockIdx.y * 64 + bg + g * 4 + q) * D_ + n0 + n] = acc[g][q];
}

// ---- reduce matvec partials: y[b] = relu(bias + sum_kch pmv[kch][b]) ----
__global__ __launch_bounds__(256) void mvg_red(const float* __restrict__ pmv,
                                               const float* __restrict__ bias,
                                               float* __restrict__ y, int nkch) {
    int j = threadIdx.x * 4;
    int b = blockIdx.y;
    f32x4 acc = *(const f32x4*)(bias + j);
    for (int kch = 0; kch < nkch; kch++)
        acc += *(const f32x4*)(pmv + ((size_t)kch * 64 + b) * D_ + j);
    #pragma unroll
    for (int q = 0; q < 4; q++) acc[q] = fmaxf(acc[q], 0.f);
    *(f32x4*)(y + (size_t)b * D_ + j) = acc;
}

// ---------------- u = WK@bQ, w = WQ@bK, alpha = bK.bQ ----------------
__global__ __launch_bounds__(256) void vecs_kernel(const float* __restrict__ WKm,
                                                   const float* __restrict__ WQm,
                                                   const float* __restrict__ bKv,
                                                   const float* __restrict__ bQv,
                                                   float* __restrict__ u,
                                                   float* __restrict__ w,
                                                   float* __restrict__ alpha) {
    int tid = threadIdx.x, wave = tid >> 6, lane = tid & 63;
    int row = blockIdx.x * 4 + wave;
    float s1 = 0.f, s2 = 0.f;
    for (int c = lane; c < D_; c += 64) {
        s1 += WKm[(size_t)row * D_ + c] * bQv[c];
        s2 += WQm[(size_t)row * D_ + c] * bKv[c];
    }
    #pragma unroll
    for (int off = 32; off; off >>= 1) {
        s1 += __shfl_xor(s1, off);
        s2 += __shfl_xor(s2, off);
    }
    if (lane == 0) { u[row] = s1; w[row] = s2; }
    if (blockIdx.x == 0 && wave == 0) {
        float a = 0.f;
        for (int c = lane; c < D_; c += 64) a += bKv[c] * bQv[c];
        #pragma unroll
        for (int off = 32; off; off >>= 1) a += __shfl_xor(a, off);
        if (lane == 0) alpha[0] = a;
    }
}

// ---- fused row dots on bf16 Gs: Gu=g.u+alpha, Gw=g.w, lg=g.(tv*Wk)+bk (1 wave/row) ----
__global__ __launch_bounds__(256) void att_dots(const short* __restrict__ gs,
                                                const float* __restrict__ u,
                                                const float* __restrict__ w,
                                                const float* __restrict__ tv,
                                                const float* __restrict__ Wk,
                                                const float* __restrict__ alpha,
                                                const float* __restrict__ bk,
                                                float* __restrict__ Gu,
                                                float* __restrict__ Gw,
                                                float* __restrict__ lg) {
    __shared__ float su[D_], sw[D_], s2[D_];
    int tid = threadIdx.x, wave = tid >> 6, lane = tid & 63;
    size_t row0 = (size_t)blockIdx.x * 4;
    int b = (int)(row0 >> 9);
    for (int c = tid; c < D_; c += 256) {
        su[c] = u[c];
        sw[c] = w[c];
        s2[c] = tv[(size_t)b * D_ + c] * Wk[c];
    }
    __syncthreads();
    size_t row = row0 + wave;
    const short* g = gs + row * D_;
    float d1 = 0.f, d2 = 0.f, d3 = 0.f;
    #pragma unroll
    for (int it = 0; it < 4; it++) {
        int c = lane * 4 + it * 256;
        short4v gv = *(const short4v*)(g + c);
        #pragma unroll
        for (int q = 0; q < 4; q++) {
            float gq = f32_of(gv[q]);
            d1 += gq * su[c + q];
            d2 += gq * sw[c + q];
            d3 += gq * s2[c + q];
        }
    }
    #pragma unroll
    for (int off = 32; off; off >>= 1) {
        d1 += __shfl_xor(d1, off);
        d2 += __shfl_xor(d2, off);
        d3 += __shfl_xor(d3, off);
    }
    if (lane == 0) {
        Gu[row] = d1 + alpha[0];
        Gw[row] = d2;
        lg[row] = d3 + bk[0];
    }
}

// ---- k-softmax over T per batch, in place ----
__global__ __launch_bounds__(256) void ksoftmax_kernel(float* __restrict__ lg) {
    __shared__ float red[4];
    int b = blockIdx.x, tid = threadIdx.x;
    int wave = tid >> 6, lane = tid & 63;
    float* L = lg + (size_t)b * T_;
    float v0 = L[tid], v1 = L[tid + 256];
    float mx = fmaxf(v0, v1);
    #pragma unroll
    for (int off = 32; off; off >>= 1) mx = fmaxf(mx, __shfl_xor(mx, off));
    if (lane == 0) red[wave] = mx;
    __syncthreads();
    mx = fmaxf(fmaxf(red[0], red[1]), fmaxf(red[2], red[3]));
    __syncthreads();
    float e0 = expf(v0 - mx), e1 = expf(v1 - mx);
    float zs = e0 + e1;
    #pragma unroll
    for (int off = 32; off; off >>= 1) zs += __shfl_xor(zs, off);
    if (lane == 0) red[wave] = zs;
    __syncthreads();
    float invZ = 1.f / (red[0] + red[1] + red[2] + red[3]);
    L[tid] = e0 * invZ;
    L[tid + 256] = e1 * invZ;
}

// ---- partial c from bf16 Gs ----
__global__ __launch_bounds__(256) void csum_part(const short* __restrict__ gs,
                                                 const float* __restrict__ k,
                                                 float* __restrict__ part) {
    __shared__ float kv[TCH];
    int d = threadIdx.x * 4;
    int ch = blockIdx.y, b = blockIdx.z;
    if (threadIdx.x < TCH) kv[threadIdx.x] = k[(size_t)b * T_ + ch * TCH + threadIdx.x];
    __syncthreads();
    const short* gb = gs + ((size_t)b * T_ + ch * TCH) * D_ + d;
    f32x4 acc = {};
    #pragma unroll 4
    for (int i = 0; i < TCH; i++) {
        short4v gv = *(const short4v*)(gb + (size_t)i * D_);
        #pragma unroll
        for (int q = 0; q < 4; q++) acc[q] += kv[i] * f32_of(gv[q]);
    }
    *(f32x4*)(part + ((size_t)b * NCH + ch) * D_ + d) = acc;
}

// ---- reduce partials: c[b,d] = sum_ch part ----
__global__ __launch_bounds__(256) void csum_reduce(const float* __restrict__ part,
                                                   float* __restrict__ cbuf) {
    int d = threadIdx.x * 4;
    int b = blockIdx.y;
    f32x4 acc = {};
    #pragma unroll
    for (int ch = 0; ch < NCH; ch++)
        acc += *(const f32x4*)(part + ((size_t)b * NCH + ch) * D_ + d);
    *(f32x4*)(cbuf + (size_t)b * D_ + d) = acc;
}

// ---------------- plain cast f32 -> bf16, vectorized ----------------
__global__ __launch_bounds__(256) void cast_kernel(const float* __restrict__ in,
                                                   short* __restrict__ out, size_t n8) {
    size_t i = (size_t)blockIdx.x * 256 + threadIdx.x;
    size_t stride = (size_t)gridDim.x * 256;
    for (; i < n8; i += stride) {
        f32x4 v0 = ((const f32x4*)in)[2 * i];
        f32x4 v1 = ((const f32x4*)in)[2 * i + 1];
        short8 o;
        #pragma unroll
        for (int j = 0; j < 4; j++) {
            o[j] = bf16_of(v0[j]);
            o[4 + j] = bf16_of(v1[j]);
        }
        ((short8*)out)[i] = o;
    }
}

// ---------------- out[z][c][r] = bf16(in[z][r][c]) ----------------
__global__ __launch_bounds__(256) void transpose_kernel(const float* __restrict__ in, size_t sIn,
                                                        short* __restrict__ out, size_t sOut,
                                                        int R, int C) {
    __shared__ float tile[32][33];
    int z = blockIdx.z;
    in += (size_t)z * sIn;
    out += (size_t)z * sOut;
    int c0 = blockIdx.x * 32, r0 = blockIdx.y * 32;
    int tx = threadIdx.x & 31, ty = threadIdx.x >> 5;
    #pragma unroll
    for (int i = 0; i < 4; i++) {
        int r = ty + i * 8;
        tile[r][tx] = in[(size_t)(r0 + r) * C + c0 + tx];
    }
    __syncthreads();
    #pragma unroll
    for (int i = 0; i < 4; i++) {
        int c = ty + i * 8;
        out[(size_t)(c0 + c) * R + r0 + tx] = bf16_of(tile[tx][c]);
    }
}

// ================= MFMA NT bf16 GEMM: 256x256 tile, deep-pipelined =================
// BK=64 split in 2 k-halves; 512 thr = 8 waves (2M x 4N); per-wave 128x64 via
// 4x2 32x32x16 frags (acc 128 VGPR). LDS 128KB: [buf][A|B][khalf][256 rows][32 k].
// Phases per tile: p0=(Mlo,k0) p1=(Mhi,k0) | barrier | p2=(Mlo,k1) p3=(Mhi,k1).
// Stage issue: p0->A-k1(t+1), p1->B-k1(t+1) (other buf; dead since last tile);
//              p2->A-k0(t+2), p3->B-k0(t+2) (current buf; k0 dead after mid barrier).
// Tile-start: counted s_waitcnt vmcnt(4) (k0(t+1) stays in flight) + s_barrier.
// Slot swizzle: LDS 16B slot s holds global slot s ^ ((row>>1)&3); linear dest,
// inverse-swizzled global source, swizzled ds_read (both-sides rule).
// MODE 0: f32 | 1: f32 + Gu[row]+Gw[col] | 2: bf16 | 3: f32 (acc+bV[col])*gate
template <int MODE>
__global__ __launch_bounds__(512) void gemm_nt(
        const short* __restrict__ A, size_t sAz,
        const short* __restrict__ Bt, size_t sBz,
        int K, int ldout,
        float* __restrict__ Cf, short* __restrict__ Cb, size_t sCz,
        const float* __restrict__ e1, const float* __restrict__ e2) {
    __shared__ __align__(16) short lds[65536];  // 128 KB
    unsigned gx = gridDim.x, gy = gridDim.y;
    unsigned lin = blockIdx.x + gx * (blockIdx.y + gy * blockIdx.z);
    unsigned tot = gx * gy * gridDim.z;
    unsigned swz = (lin & 7u) * (tot >> 3) + (lin >> 3);
    unsigned bx = swz % gx;
    unsigned tmp = swz / gx;
    unsigned by = tmp % gy;
    unsigned bz = tmp / gy;

    int z = bz;
    A += (size_t)z * sAz;
    Bt += (size_t)z * sBz;
    int tid = threadIdx.x;
    int lane = tid & 63, wave = tid >> 6;
    int wr = wave >> 2, wc = wave & 3;
    size_t rowBase = (size_t)bx * 256;
    size_t colBase = (size_t)by * 256;

    int srcslot = (lane & 3) ^ ((lane >> 3) & 3);  // inverse-swizzled global 16B slot
    int srow = lane >> 2;                          // row within 16-row chunk
    int rxor = (lane >> 1) & 3;                    // read-side swizzle
    int khi = lane >> 5;                           // k sub-slot (0/1)
    const int NT = K >> 6;

// stage one 16KB half-tile (256 rows x 32 k), 2 gload16/thread; ldsoff in shorts
#define STAGE(gptr, base, kb, h, ldsoff)                                           \
    {                                                                              \
        _Pragma("unroll")                                                          \
        for (int q = 0; q < 2; q++) {                                              \
            int ch = wave * 2 + q;                                                 \
            const short* _s = (gptr) + ((base) + ch * 16 + srow) * (size_t)K       \
                              + (kb) + (h) * 32 + srcslot * 8;                     \
            gload16(_s, lds + (ldsoff) + ch * 512);                                \
        }                                                                          \
    }

// compute one phase: M-half mh, k-half h, buffer offset boff; 8 ds_read + 8 MFMA
#define PHASE(mh, h, boff)                                                         \
    {                                                                              \
        const short* _as = lds + (boff) + (h) * 8192;                              \
        const short* _bs = lds + (boff) + 16384 + (h) * 8192;                      \
        short8 af[2][2], bq[2][2];                                                 \
        _Pragma("unroll")                                                          \
        for (int sl = 0; sl < 2; sl++) {                                           \
            int slot = ((sl * 2 + khi) ^ rxor) * 8;                                \
            _Pragma("unroll")                                                      \
            for (int i = 0; i < 2; i++) {                                          \
                int row = wr * 128 + ((mh) * 2 + i) * 32 + (lane & 31);            \
                af[i][sl] = *(const short8*)(_as + row * 32 + slot);               \
            }                                                                      \
            _Pragma("unroll")                                                      \
            for (int j = 0; j < 2; j++) {                                          \
                int row = wc * 64 + j * 32 + (lane & 31);                          \
                bq[j][sl] = *(const short8*)(_bs + row * 32 + slot);               \
            }                                                                      \
        }                                                                          \
        __builtin_amdgcn_s_setprio(1);                                             \
        _Pragma("unroll")                                                          \
        for (int sl = 0; sl < 2; sl++)                                             \
            _Pragma("unroll")                                                      \
            for (int i = 0; i < 2; i++)                                            \
                _Pragma("unroll")                                                  \
                for (int j = 0; j < 2; j++)                                        \
                    acc[(mh) * 2 + i][j] = __builtin_amdgcn_mfma_f32_32x32x16_bf16(\
                        af[i][sl], bq[j][sl], acc[(mh) * 2 + i][j], 0, 0, 0);      \
        __builtin_amdgcn_s_setprio(0);                                             \
    }

    f32x16 acc[4][2] = {};

    // prologue: tile0 full (Ak0,Bk0,Ak1,Bk1 -> buf0), tile1 k0 (A,B -> buf1)
    STAGE(A, rowBase, 0, 0, 0);
    STAGE(Bt, colBase, 0, 0, 16384);
    STAGE(A, rowBase, 0, 1, 8192);
    STAGE(Bt, colBase, 0, 1, 16384 + 8192);
    STAGE(A, rowBase, 64, 0, 32768);
    STAGE(Bt, colBase, 64, 0, 32768 + 16384);

    for (int t = 0; t < NT; t++) {
        int boff = (t & 1) * 32768;
        int ooff = boff ^ 32768;
        if (t == NT - 1) {
            asm volatile("s_waitcnt vmcnt(0)" ::: "memory");
        } else {
            asm volatile("s_waitcnt vmcnt(4)" ::: "memory");
        }
        __builtin_amdgcn_s_barrier();
        if (t + 1 < NT) STAGE(A, rowBase, (t + 1) * 64, 1, ooff + 8192);
        PHASE(0, 0, boff);
        if (t + 1 < NT) STAGE(Bt, colBase, (t + 1) * 64, 1, ooff + 16384 + 8192);
        PHASE(1, 0, boff);
        asm volatile("s_waitcnt lgkmcnt(0)" ::: "memory");
        __builtin_amdgcn_s_barrier();
        if (t + 2 < NT) STAGE(A, rowBase, (t + 2) * 64, 0, boff);
        PHASE(0, 1, boff);
        if (t + 2 < NT) STAGE(Bt, colBase, (t + 2) * 64, 0, boff + 16384);
        PHASE(1, 1, boff);
        asm volatile("s_waitcnt lgkmcnt(0)" ::: "memory");
    }

    #pragma unroll
    for (int i = 0; i < 4; i++) {
        #pragma unroll
        for (int j = 0; j < 2; j++) {
            #pragma unroll
            for (int r = 0; r < 16; r++) {
                size_t row = rowBase + wr * 128 + i * 32 + (r & 3) + 8 * (r >> 2) + 4 * khi;
                size_t col = colBase + wc * 64 + j * 32 + (lane & 31);
                float v = acc[i][j][r];
                if (MODE == 0) {
                    Cf[z * sCz + row * ldout + col] = v;
                } else if (MODE == 1) {
                    Cf[z * sCz + row * ldout + col] = v + e1[z * T_ + row] + e2[z * T_ + col];
                } else if (MODE == 2) {
                    Cb[z * sCz + row * ldout + col] = bf16_of(v);
                } else {
                    Cf[z * sCz + row * ldout + col] = (v + e1[col]) * e2[(size_t)z * D_ + col];
                }
            }
        }
    }
#undef STAGE
#undef PHASE
}

// ---------------- per-row: att out (f32) + probs out (bf16); 4 rows/block ----------------
__global__ __launch_bounds__(256) void softmax_att(const float* __restrict__ S,
                                                   short* __restrict__ probs,
                                                   float* __restrict__ att) {
    const float SCALE = 0.03125f;  // 1/32
    int wave = threadIdx.x >> 6, lane = threadIdx.x & 63;
    int t = blockIdx.x * 4 + wave, z = blockIdx.y;
    const float* row = S + ((size_t)z * T_ + t) * T_;
    short* prow = probs + ((size_t)z * T_ + t) * T_;
    float v[8];
    float mx = -1e30f;
    #pragma unroll
    for (int k = 0; k < 8; k++) {
        v[k] = row[lane + k * 64];
        mx = fmaxf(mx, v[k]);
    }
    #pragma unroll
    for (int off = 32; off; off >>= 1) mx = fmaxf(mx, __shfl_xor(mx, off));
    float z1 = 0.f, z2 = 0.f, dg = 0.f;
    #pragma unroll
    for (int k = 0; k < 8; k++) {
        float x = v[k] - mx;
        float e2 = expf(x * SCALE);
        float p = e2 * e2;
        p = p * p;
        p = p * p;
        p = p * p;
        p = p * p;  // e^x
        z1 += p;
        z2 += e2;
        if (lane + k * 64 == t) dg = p;
        v[k] = e2;
    }
    #pragma unroll
    for (int off = 32; off; off >>= 1) {
        z1 += __shfl_xor(z1, off);
        z2 += __shfl_xor(z2, off);
        dg += __shfl_xor(dg, off);
    }
    float inv2 = 1.f / z2;
    #pragma unroll
    for (int k = 0; k < 8; k++) prow[lane + k * 64] = bf16_of(v[k] * inv2);
    if (lane == 0) att[z * T_ + t] = SCALE * (1.f - dg / z1);
}

// ---------------- masks passthrough (f32) ----------------
__global__ __launch_bounds__(256) void masks_kernel(const int* __restrict__ masks,
                                                    float* __restrict__ out_masks) {
    int i = blockIdx.x * 256 + threadIdx.x;
    if (i < B_ * T_) out_masks[i] = (float)masks[i];
}

extern "C" void kernel_launch(void* const* d_in, const int* in_sizes, int n_in,
                              void* d_out, int out_size, void* d_ws, size_t ws_size,
                              hipStream_t stream) {
    const float* gcn = (const float*)d_in[0];
    const int* subj_pos = (const int*)d_in[1];
    const int* masks = (const int*)d_in[3];
    const float* Wq = (const float*)d_in[4];
    const float* bq = (const float*)d_in[5];
    const float* Wc = (const float*)d_in[6];
    const float* bc = (const float*)d_in[7];
    const float* Wk = (const float*)d_in[8];
    const float* bk = (const float*)d_in[9];
    const float* Wm = (const float*)d_in[10];
    const float* bm = (const float*)d_in[11];
    const float* WK = (const float*)d_in[12];
    const float* bK = (const float*)d_in[13];
    const float* WQ = (const float*)d_in[14];
    const float* bQ = (const float*)d_in[15];
    const float* WV = (const float*)d_in[16];
    const float* bV = (const float*)d_in[17];

    float* out = (float*)d_out;

    // ---- workspace layout ----
    char* p = (char*)d_ws;
    auto alloc = [&](size_t bytes) {
        char* r = p;
        p += (bytes + 255) & ~(size_t)255;
        return r;
    };
    float* subj = (float*)alloc(B_ * D_ * 4);
    float* qv   = (float*)alloc(B_ * D_ * 4);
    float* tv   = (float*)alloc(B_ * D_ * 4);
    float* cb   = (float*)alloc(B_ * D_ * 4);
    float* mb   = (float*)alloc(B_ * D_ * 4);
    float* u    = (float*)alloc(D_ * 4);
    float* w    = (float*)alloc(D_ * 4);
    float* alph = (float*)alloc(256);
    float* Gu   = (float*)alloc(B_ * T_ * 4);
    float* Gw   = (float*)alloc(B_ * T_ * 4);
    float* lg   = (float*)alloc(B_ * T_ * 4);
    float* part = (float*)alloc((size_t)B_ * NCH * D_ * 4);
    float* pmax = (float*)alloc((size_t)B_ * 4 * D_ * 4);
    float* pmv  = (float*)alloc((size_t)24 * 64 * D_ * 4);
    short* WKb  = (short*)alloc((size_t)D_ * D_ * 2);
    short* WQb  = (short*)alloc((size_t)D_ * D_ * 2);
    short* Ptb  = (short*)alloc((size_t)D_ * D_ * 2);
    short* WVt  = (short*)alloc((size_t)D_ * D_ * 2);
    short* Gs   = (short*)alloc((size_t)B_ * T_ * D_ * 2);  // full, all batches
    short* Gt   = (short*)alloc((size_t)B_ * D_ * T_ * 2);  // full, all batches

    size_t fixedBytes = (size_t)(p - (char*)d_ws);
    const size_t perBatch = (size_t)T_ * D_ * 2   // Ys
                          + (size_t)T_ * T_ * 4   // S
                          + (size_t)T_ * T_ * 2   // probs
                          + (size_t)T_ * D_ * 2;  // Zs
    int nc = 64;
    while (nc > 1 && fixedBytes + (size_t)nc * perBatch + 4096 > ws_size) nc >>= 1;

    short* Ys_c    = (short*)alloc((size_t)nc * T_ * D_ * 2);
    float* S_c     = (float*)alloc((size_t)nc * T_ * T_ * 4);
    short* probs_c = (short*)alloc((size_t)nc * T_ * T_ * 2);
    short* Zs_c    = (short*)alloc((size_t)nc * T_ * D_ * 2);

    // ---- weight precompute ----
    cast_kernel<<<512, 256, 0, stream>>>(WK, WKb, (size_t)D_ * D_ / 8);
    cast_kernel<<<512, 256, 0, stream>>>(WQ, WQb, (size_t)D_ * D_ / 8);
    gemm_nt<2><<<dim3(4, 4, 1), 512, 0, stream>>>(WQb, 0, WKb, 0, D_, D_,
                                                  nullptr, Ptb, 0, nullptr, nullptr);
    transpose_kernel<<<dim3(32, 32, 1), 256, 0, stream>>>(WV, 0, WVt, 0, D_, D_);

    // ---- prep ALL batches: Gs/Gt/out2/pool-partials in one gcn pass ----
    prep_kernel<<<dim3(D_ / 32, T_ / 128, B_), 256, 0, stream>>>(
        gcn, subj_pos, Gs, Gt, out + OUT2_OFF, pmax);

    // ---- small path ----
    pool_red<<<dim3(1, B_), 256, 0, stream>>>(pmax, subj);
    mvg_part<<<dim3(D_ / 64, 16), 256, 0, stream>>>(subj, subj, Wq, pmv);
    mvg_red<<<dim3(1, B_), 256, 0, stream>>>(pmv, bq, qv, 16);
    mvg_part<<<dim3(D_ / 64, 8), 256, 0, stream>>>(qv, qv, Wc, pmv);
    mvg_red<<<dim3(1, B_), 256, 0, stream>>>(pmv, bc, tv, 8);
    vecs_kernel<<<D_ / 4, 256, 0, stream>>>(WK, WQ, bK, bQ, u, w, alph);
    att_dots<<<B_ * T_ / 4, 256, 0, stream>>>(Gs, u, w, tv, Wk, alph, bk, Gu, Gw, lg);
    ksoftmax_kernel<<<B_, 256, 0, stream>>>(lg);
    csum_part<<<dim3(1, NCH, B_), 256, 0, stream>>>(Gs, lg, part);
    csum_reduce<<<dim3(1, B_), 256, 0, stream>>>(part, cb);
    mvg_part<<<dim3(D_ / 64, 24), 256, 0, stream>>>(cb, subj, Wm, pmv);
    mvg_red<<<dim3(1, B_), 256, 0, stream>>>(pmv, bm, mb, 24);

    // ---- chunked attention ----
    for (int b0 = 0; b0 < B_; b0 += nc) {
        const short* Gsc = Gs + (size_t)b0 * T_ * D_;
        const short* Gtc = Gt + (size_t)b0 * D_ * T_;
        // Y = G@M
        gemm_nt<2><<<dim3(nc * T_ / 256, D_ / 256, 1), 512, 0, stream>>>(
            Gsc, 0, Ptb, 0, D_, D_, nullptr, Ys_c, 0, nullptr, nullptr);
        // S = Y@G^T + Gu + Gw
        gemm_nt<1><<<dim3(T_ / 256, T_ / 256, nc), 512, 0, stream>>>(
            Ys_c, (size_t)T_ * D_, Gsc, (size_t)T_ * D_, D_, T_,
            S_c, nullptr, (size_t)T_ * T_, Gu + (size_t)b0 * T_, Gw + (size_t)b0 * T_);
        // softmax: att (f32) + probs (bf16)
        softmax_att<<<dim3(T_ / 4, nc), 256, 0, stream>>>(S_c, probs_c, out + OUT3_OFF + (size_t)b0 * T_);
        // Z = probs@G
        gemm_nt<2><<<dim3(T_ / 256, D_ / 256, nc), 512, 0, stream>>>(
            probs_c, (size_t)T_ * T_, Gtc, (size_t)D_ * T_, T_, D_,
            nullptr, Zs_c, (size_t)T_ * D_, nullptr, nullptr);
        // out0 = (Z@WV + bV) * m
        gemm_nt<3><<<dim3(T_ / 256, D_ / 256, nc), 512, 0, stream>>>(
            Zs_c, (size_t)T_ * D_, WVt, 0, D_, D_,
            out + OUT0_OFF + (size_t)b0 * T_ * D_, nullptr, (size_t)T_ * D_,
            bV, mb + (size_t)b0 * D_);
    }

    // ---- masks passthrough ----
    masks_kernel<<<(B_ * T_ + 255) / 256, 256, 0, stream>>>(masks, out + OUT1_OFF);
}